// Round 14
// baseline (2038.705 us; speedup 1.0000x reference)
//
#include <hip/hip_runtime.h>
#include <hip/hip_bf16.h>

#define MD 1024   // M
#define LD 1024   // L
#define ND 2048   // N
#define JZ 4096   // combined [iou|f] width

typedef __bf16 bf16x8 __attribute__((ext_vector_type(8)));
typedef __bf16 bf16x4 __attribute__((ext_vector_type(4)));
typedef float  f32x4  __attribute__((ext_vector_type(4)));

__device__ __forceinline__ float fsig(float x)  { return 1.0f / (1.0f + __expf(-x)); }
__device__ __forceinline__ float ftanh_(float x){ float e = __expf(2.0f * x); return 1.0f - 2.0f / (e + 1.0f); }

__device__ __forceinline__ bf16x8 bzero8() {
    bf16x8 z;
    #pragma unroll
    for (int q = 0; q < 8; q++) z[q] = (__bf16)0.f;
    return z;
}

// async 16B global -> LDS (dest = wave-uniform base + lane*16)
__device__ __forceinline__ void gload16(const __bf16* g, __bf16* l)
{
    __builtin_amdgcn_global_load_lds(
        (const __attribute__((address_space(1))) void*)g,
        (__attribute__((address_space(3))) void*)l, 16, 0, 0);
}

// paired-rcp attention accumulate: w1/(1+a)+w2/(1+b) = (w1*v + w2*u)/(u*v)
__device__ __forceinline__ void attn_quad(const float4 se, const float4 ev,
                                          const float4 wa, float& acc)
{
    float u0 = fmaf(se.x, ev.x, 1.0f);
    float v0 = fmaf(se.y, ev.y, 1.0f);
    float n0 = fmaf(wa.x, v0, wa.y * u0);
    float r0 = __builtin_amdgcn_rcpf(u0 * v0);
    acc = fmaf(n0, r0, acc);
    float u1 = fmaf(se.z, ev.z, 1.0f);
    float v1 = fmaf(se.w, ev.w, 1.0f);
    float n1 = fmaf(wa.z, v1, wa.w * u1);
    float r1 = __builtin_amdgcn_rcpf(u1 * v1);
    acc = fmaf(n1, r1, acc);
}

// ---------------- merged f32 -> bf16 conversions (one launch) ----------------
__global__ void cvt_all_k(const float* __restrict__ iouh_w, const float* __restrict__ fh_w,
                          const float* __restrict__ ioux_w, const float* __restrict__ fx_w,
                          const float* __restrict__ attnh_w, const float* __restrict__ inputs,
                          const float* __restrict__ Hmat,
                          __bf16* __restrict__ WzB, __bf16* __restrict__ WxB,
                          __bf16* __restrict__ W1H, __bf16* __restrict__ W2H,
                          __bf16* __restrict__ inpB, __bf16* __restrict__ HmatB)
{
    const size_t MM = (size_t)MD * MD;
    const size_t b0 = 3 * MM, b1 = 4 * MM, b2 = 7 * MM, b3 = 8 * MM;
    const size_t b4 = 9 * MM, b5 = 10 * MM, b6 = 12 * MM, b7 = 13 * MM;
    for (size_t idx = (size_t)blockIdx.x * 256 + threadIdx.x; idx < b7;
         idx += (size_t)gridDim.x * 256) {
        if (idx < b1) {
            WzB[idx] = (__bf16)((idx < b0) ? iouh_w[idx] : fh_w[idx - b0]);
        } else if (idx < b3) {
            size_t r = idx - b1;
            WxB[r] = (__bf16)((idx < b2) ? ioux_w[r] : fx_w[idx - b2]);
        } else if (idx < b4) {
            size_t r = idx - b3; size_t j = r >> 10, k = r & (MD - 1);
            W1H[r] = (__bf16)attnh_w[j * 2 * MD + k];
        } else if (idx < b5) {
            size_t r = idx - b4; size_t j = r >> 10, k = r & (MD - 1);
            W2H[r] = (__bf16)attnh_w[j * 2 * MD + MD + k];
        } else if (idx < b6) {
            size_t r = idx - b5;
            inpB[r] = (__bf16)inputs[r];
        } else {
            size_t r = idx - b6;
            HmatB[r] = (__bf16)Hmat[r];
        }
    }
}

__global__ void concat_bias_k(const float* __restrict__ a, const float* __restrict__ b,
                              float* __restrict__ dst)
{
    int i = blockIdx.x * 256 + threadIdx.x;
    dst[i] = (i < 3 * MD) ? a[i] : b[i - 3 * MD];
}

// epilogue modes:
//  0: (acc+bias)*scale (+X)
//  1: exp(clamp((acc+bias)*scale (+X), +-80))
//  2: FIN: C = add1[col] - acc + X ; C2 = X - acc ; C3 = bf16(X - acc)
// ---------------- bf16 MFMA NT GEMM, 128x128 tile ----------------
__global__ __launch_bounds__(256) void gemm_mfma(
    const __bf16* __restrict__ Ab, int lda,
    const __bf16* __restrict__ Wh,
    const float* __restrict__ bias,
    const float* __restrict__ X, int ldx, const float* __restrict__ add1,
    float* __restrict__ C, float* __restrict__ C2, __bf16* __restrict__ C3, int ldc,
    int I, int K, float scale, int epi)
{
    __shared__ __align__(16) __bf16 Ash[128][4][8];
    __shared__ __align__(16) __bf16 Bsh[128][4][8];
    const int tid = threadIdx.x;
    const int j0 = blockIdx.x * 128, i0 = blockIdx.y * 128;
    const int lane = tid & 63, wv = tid >> 6;
    const int wm = wv >> 1, wn = wv & 1;
    const int g = lane >> 4, fr = lane & 15;

    f32x4 acc[4][4];
    #pragma unroll
    for (int m = 0; m < 4; m++)
        #pragma unroll
        for (int n = 0; n < 4; n++)
            acc[m][n] = (f32x4){0.f, 0.f, 0.f, 0.f};

    const int srow = tid >> 2;
    const int sg   = tid & 3;
    int ar0 = i0 + srow;       if (ar0 >= I) ar0 = I - 1;
    int ar1 = i0 + srow + 64;  if (ar1 >= I) ar1 = I - 1;
    const __bf16* agp0 = Ab + (size_t)ar0 * lda + sg * 8;
    const __bf16* agp1 = Ab + (size_t)ar1 * lda + sg * 8;
    const __bf16* wgp0 = Wh + (size_t)(j0 + srow) * K + sg * 8;
    const __bf16* wgp1 = Wh + (size_t)(j0 + srow + 64) * K + sg * 8;
    __bf16* aD0 = &Ash[wv * 16][0][0];
    __bf16* aD1 = &Ash[64 + wv * 16][0][0];
    __bf16* bD0 = &Bsh[wv * 16][0][0];
    __bf16* bD1 = &Bsh[64 + wv * 16][0][0];

    for (int kt = 0; kt < K; kt += 32) {
        __syncthreads();
        gload16(agp0 + kt, aD0);
        gload16(agp1 + kt, aD1);
        gload16(wgp0 + kt, bD0);
        gload16(wgp1 + kt, bD1);
        __syncthreads();

        bf16x8 ah[4], bh[4];
        #pragma unroll
        for (int m = 0; m < 4; m++) ah[m] = *(bf16x8*)&Ash[wm * 64 + m * 16 + fr][g][0];
        #pragma unroll
        for (int n = 0; n < 4; n++) bh[n] = *(bf16x8*)&Bsh[wn * 64 + n * 16 + fr][g][0];
        #pragma unroll
        for (int m = 0; m < 4; m++)
            #pragma unroll
            for (int n = 0; n < 4; n++)
                acc[m][n] = __builtin_amdgcn_mfma_f32_16x16x32_bf16(ah[m], bh[n], acc[m][n], 0, 0, 0);
    }

    #pragma unroll
    for (int m = 0; m < 4; m++) {
        int rbase = i0 + wm * 64 + m * 16 + g * 4;
        #pragma unroll
        for (int nn = 0; nn < 4; nn++) {
            int col = j0 + wn * 64 + nn * 16 + fr;
            float b = bias ? bias[col] : 0.f;
            #pragma unroll
            for (int j = 0; j < 4; j++) {
                int r = rbase + j;
                if (r >= I) continue;
                float a = acc[m][nn][j];
                if (epi == 2) {
                    float hc = X[(size_t)r * ldx + col];
                    C[(size_t)r * ldc + col]  = add1[col] - a + hc;
                    float d = hc - a;
                    C2[(size_t)r * ldc + col] = d;
                    C3[(size_t)r * ldc + col] = (__bf16)d;
                } else {
                    float v = (a + b) * scale;
                    if (X) v += X[(size_t)r * ldx + col];
                    if (epi == 1) v = __expf(fminf(fmaxf(v, -80.f), 80.f));
                    C[(size_t)r * ldc + col] = v;
                }
            }
        }
    }
}

// ---------------- bf16 MFMA NT GEMM, 64x64 tile ----------------
__global__ __launch_bounds__(256) void gemm64_mfma(
    const __bf16* __restrict__ Ab, int lda,
    const __bf16* __restrict__ Wh,
    const float* __restrict__ bias,
    const float* __restrict__ X, int ldx, const float* __restrict__ add1,
    float* __restrict__ C, float* __restrict__ C2, __bf16* __restrict__ C3, int ldc,
    int I, int K, float scale, int epi)
{
    __shared__ __align__(16) __bf16 Ash[64][4][8];
    __shared__ __align__(16) __bf16 Bsh[64][4][8];
    const int tid = threadIdx.x;
    const int j0 = blockIdx.x * 64, i0 = blockIdx.y * 64;
    const int lane = tid & 63, wv = tid >> 6;
    const int wm = wv >> 1, wn = wv & 1;
    const int g = lane >> 4, fr = lane & 15;

    f32x4 acc[2][2];
    #pragma unroll
    for (int m = 0; m < 2; m++)
        #pragma unroll
        for (int n = 0; n < 2; n++)
            acc[m][n] = (f32x4){0.f, 0.f, 0.f, 0.f};

    const int srow = tid >> 2;
    const int sg   = tid & 3;
    int ar = i0 + srow;  if (ar >= I) ar = I - 1;
    const __bf16* agp = Ab + (size_t)ar * lda + sg * 8;
    const __bf16* wgp = Wh + (size_t)(j0 + srow) * K + sg * 8;
    __bf16* aD = &Ash[wv * 16][0][0];
    __bf16* bD = &Bsh[wv * 16][0][0];

    for (int kt = 0; kt < K; kt += 32) {
        __syncthreads();
        gload16(agp + kt, aD);
        gload16(wgp + kt, bD);
        __syncthreads();

        bf16x8 ah[2], bh[2];
        #pragma unroll
        for (int m = 0; m < 2; m++) ah[m] = *(bf16x8*)&Ash[wm * 32 + m * 16 + fr][g][0];
        #pragma unroll
        for (int n = 0; n < 2; n++) bh[n] = *(bf16x8*)&Bsh[wn * 32 + n * 16 + fr][g][0];
        #pragma unroll
        for (int m = 0; m < 2; m++)
            #pragma unroll
            for (int n = 0; n < 2; n++)
                acc[m][n] = __builtin_amdgcn_mfma_f32_16x16x32_bf16(ah[m], bh[n], acc[m][n], 0, 0, 0);
    }

    #pragma unroll
    for (int m = 0; m < 2; m++) {
        int rbase = i0 + wm * 32 + m * 16 + g * 4;
        #pragma unroll
        for (int nn = 0; nn < 2; nn++) {
            int col = j0 + wn * 32 + nn * 16 + fr;
            float b = bias ? bias[col] : 0.f;
            #pragma unroll
            for (int j = 0; j < 4; j++) {
                int r = rbase + j;
                if (r >= I) continue;
                float a = acc[m][nn][j];
                if (epi == 2) {
                    float hc = X[(size_t)r * ldx + col];
                    C[(size_t)r * ldc + col]  = add1[col] - a + hc;
                    float d = hc - a;
                    C2[(size_t)r * ldc + col] = d;
                    C3[(size_t)r * ldc + col] = (__bf16)d;
                } else {
                    float v = (a + b) * scale;
                    if (X) v += X[(size_t)r * ldx + col];
                    if (epi == 1) v = __expf(fminf(fmaxf(v, -80.f), 80.f));
                    C[(size_t)r * ldc + col] = v;
                }
            }
        }
    }
}

// ---------------- i-tiled batched GEMV (f32 A x bf16 W), tail I<=32 ----------------
__global__ __launch_bounds__(256) void gemv16(
    const float* __restrict__ Af, int lda, int I,
    const __bf16* __restrict__ Wb, int ldw,
    const float* __restrict__ bias,
    const float* __restrict__ X, int ldx, const float* __restrict__ add1,
    float* __restrict__ C, float* __restrict__ C2, __bf16* __restrict__ C3, int ldc,
    int K, float scale, int epi)
{
    const int wv = threadIdx.x >> 6, lane = threadIdx.x & 63;
    const int j = blockIdx.x * 4 + wv;
    const int i0 = blockIdx.y * 16;
    const int nI = (I - i0 < 16) ? (I - i0) : 16;
    float acc[16];
    #pragma unroll
    for (int i = 0; i < 16; i++) acc[i] = 0.0f;
    const __bf16* wp = Wb + (size_t)j * ldw + lane * 4;
    const float*  ap = Af + (size_t)i0 * lda + lane * 4;
    for (int k = lane * 4; k < K; k += 256, wp += 256, ap += 256) {
        bf16x4 w4 = *(const bf16x4*)wp;
        float w0 = (float)w4[0], w1 = (float)w4[1], w2 = (float)w4[2], w3 = (float)w4[3];
        const float* a = ap;
        #pragma unroll
        for (int i = 0; i < 16; i++, a += lda) {
            if (i < nI) {
                float4 a4 = *(const float4*)a;
                acc[i] += a4.x * w0 + a4.y * w1 + a4.z * w2 + a4.w * w3;
            }
        }
    }
    #pragma unroll
    for (int i = 0; i < 16; i++) {
        if (i < nI) {
            float s = acc[i];
            #pragma unroll
            for (int off = 32; off >= 1; off >>= 1) s += __shfl_xor(s, off);
            if (lane == 0) {
                int r = i0 + i;
                if (epi == 2) {
                    float hc = X[(size_t)r * ldx + j];
                    C[(size_t)r * ldc + j]  = add1[j] - s + hc;
                    float d = hc - s;
                    C2[(size_t)r * ldc + j] = d;
                    C3[(size_t)r * ldc + j] = (__bf16)d;
                } else {
                    float v = (s + (bias ? bias[j] : 0.f)) * scale;
                    if (X) v += X[(size_t)r * ldx + j];
                    if (epi == 1) v = __expf(fminf(fmaxf(v, -80.f), 80.f));
                    C[(size_t)r * ldc + j] = v;
                }
            }
        }
    }
}

// ---------------- exact f32 GEMV (HsumWz precompute only, I=1) ----------------
__global__ __launch_bounds__(256) void gemvHsum(
    const float* __restrict__ Af,
    const float* __restrict__ Wf, int ldw,
    float* __restrict__ C, int K)
{
    const int wv = threadIdx.x >> 6, lane = threadIdx.x & 63;
    const int j = blockIdx.x * 4 + wv;
    float a = 0.f;
    for (int k = lane * 4; k < K; k += 256) {
        float4 w4 = *(const float4*)(Wf + (size_t)j * ldw + k);
        float4 a4 = *(const float4*)(Af + k);
        a += a4.x * w4.x + a4.y * w4.y + a4.z * w4.z + a4.w * w4.w;
    }
    #pragma unroll
    for (int off = 32; off >= 1; off >>= 1) a += __shfl_xor(a, off);
    if (lane == 0) C[j] = a;
}

// ---------------- attention scores: single-row body, paired rcp ----------------
// live-set discipline: one row per pass (8 quads/mc-iter), VGPR capped via launch_bounds.
template<int LTILE>
__global__ __launch_bounds__(512, 6) void attn_s(
    int B, const float* __restrict__ Eh,
    const float* __restrict__ EH,
    const float* __restrict__ s_wa_sum,
    const float* __restrict__ Wa,
    float* __restrict__ S)
{
    __shared__ float s_e[8][MD];
    __shared__ float s_wa[MD];
    const int lt = blockIdx.x * LTILE;
    const int b0 = blockIdx.y * 8;
    const int nt = (B - b0 < 8) ? (B - b0) : 8;
    for (int idx = threadIdx.x; idx < MD; idx += 512) s_wa[idx] = Wa[idx];
    for (int i = 0; i < nt; i++)
        for (int idx = threadIdx.x; idx < MD; idx += 512)
            s_e[i][idx] = Eh[(size_t)(b0 + i) * MD + idx];
    __syncthreads();
    const int wv = threadIdx.x >> 6, lane = threadIdx.x & 63;
    const float swa = s_wa_sum[0];
    for (int l = lt + wv; l < lt + LTILE; l += 8) {
        float acc[8] = {};
        const float* er = EH + (size_t)l * MD;
        for (int mc = 0; mc < MD; mc += 256) {
            const int m = mc + lane * 4;
            float4 ev  = *(const float4*)(er + m);
            float4 wa4 = *(const float4*)&s_wa[m];
            #pragma unroll
            for (int i = 0; i < 8; i++) {
                if (LTILE >= 16 || i < nt) {
                    float4 se = *(const float4*)&s_e[i][m];
                    attn_quad(se, ev, wa4, acc[i]);
                }
            }
        }
        #pragma unroll
        for (int i = 0; i < 8; i++) {
            if (LTILE >= 16 || i < nt) {
                float v = acc[i];
                #pragma unroll
                for (int off = 32; off >= 1; off >>= 1) v += __shfl_xor(v, off);
                if (lane == 0) S[(size_t)(b0 + i) * LD + l] = swa - 2.0f * v;
            }
        }
    }
}

// ---------------- softmax (f32 + bf16 copies of P) ----------------
__global__ __launch_bounds__(256) void softmax_rows(float* __restrict__ S, __bf16* __restrict__ Sb)
{
    float* row = S + (size_t)blockIdx.x * LD;
    __bf16* rb = Sb + (size_t)blockIdx.x * LD;
    const int tid = threadIdx.x;
    const int wv = tid >> 6, lane = tid & 63;
    float v0 = row[tid], v1 = row[tid + 256], v2 = row[tid + 512], v3 = row[tid + 768];
    float mx = fmaxf(fmaxf(v0, v1), fmaxf(v2, v3));
    #pragma unroll
    for (int off = 32; off >= 1; off >>= 1) mx = fmaxf(mx, __shfl_xor(mx, off));
    __shared__ float r1[4], r2[4];
    if (lane == 0) r1[wv] = mx;
    __syncthreads();
    mx = fmaxf(fmaxf(r1[0], r1[1]), fmaxf(r1[2], r1[3]));
    float e0 = __expf(v0 - mx), e1 = __expf(v1 - mx), e2 = __expf(v2 - mx), e3 = __expf(v3 - mx);
    float sm = e0 + e1 + e2 + e3;
    #pragma unroll
    for (int off = 32; off >= 1; off >>= 1) sm += __shfl_xor(sm, off);
    if (lane == 0) r2[wv] = sm;
    __syncthreads();
    sm = r2[0] + r2[1] + r2[2] + r2[3];
    float inv = 1.0f / sm;
    float p0 = e0 * inv, p1 = e1 * inv, p2 = e2 * inv, p3 = e3 * inv;
    row[tid] = p0; row[tid + 256] = p1; row[tid + 512] = p2; row[tid + 768] = p3;
    rb[tid] = (__bf16)p0; rb[tid + 256] = (__bf16)p1;
    rb[tid + 512] = (__bf16)p2; rb[tid + 768] = (__bf16)p3;
}

// ---------------- cell finish ----------------
__global__ void cell_finish_k(const int* __restrict__ children, int t0,
    const float* __restrict__ Z, const float* __restrict__ HsumWz,
    const float* __restrict__ iouh_b, const float* __restrict__ fh_b,
    const float* __restrict__ x_all,
    float* __restrict__ Cmat, float* __restrict__ hcell, __bf16* __restrict__ hcellB)
{
    int b = blockIdx.y;
    int m = blockIdx.x * 256 + threadIdx.x;
    int t = t0 + b;
    int c0 = children[2 * t], c1 = children[2 * t + 1];
    float cnt = (float)((c0 >= 0) + (c1 >= 0));
    const float* z0 = (c0 >= 0) ? Z + (size_t)c0 * JZ : nullptr;
    const float* z1 = (c1 >= 0) ? Z + (size_t)c1 * JZ : nullptr;
    const float* xr = x_all + (size_t)t * JZ;

    float zi = 0.f, zo = 0.f, zu = 0.f;
    if (z0) { zi += z0[m]; zo += z0[MD + m]; zu += z0[2 * MD + m]; }
    if (z1) { zi += z1[m]; zo += z1[MD + m]; zu += z1[2 * MD + m]; }
    float iv = fsig (zi + cnt * HsumWz[m]           + iouh_b[m]           + xr[m]);
    float ov = fsig (zo + cnt * HsumWz[MD + m]      + iouh_b[MD + m]      + xr[MD + m]);
    float uv = ftanh_(zu + cnt * HsumWz[2 * MD + m] + iouh_b[2 * MD + m]  + xr[2 * MD + m]);

    float hwf = HsumWz[3 * MD + m] + fh_b[m] + xr[3 * MD + m];
    float c = iv * uv;
    if (c0 >= 0) c += fsig(z0[3 * MD + m] + hwf) * Cmat[(size_t)c0 * MD + m];
    if (c1 >= 0) c += fsig(z1[3 * MD + m] + hwf) * Cmat[(size_t)c1 * MD + m];
    Cmat[(size_t)t * MD + m] = c;
    float h = ov * ftanh_(c);
    hcell[(size_t)b * MD + m] = h;
    hcellB[(size_t)b * MD + m] = (__bf16)h;
}

// ---------------- misc precompute ----------------
__global__ void colsum_part_k(const float* __restrict__ H, float* __restrict__ part)
{
    int m = blockIdx.x * 256 + threadIdx.x;
    int lb = blockIdx.y;
    float s = 0.f;
    for (int l = lb * 64; l < lb * 64 + 64; l++) s += H[(size_t)l * MD + m];
    part[(size_t)lb * MD + m] = s;
}

__global__ void colsum_reduce_k(const float* __restrict__ part, float* __restrict__ Hsum)
{
    int m = blockIdx.x * 256 + threadIdx.x;
    float s = 0.f;
    for (int lb = 0; lb < 16; lb++) s += part[(size_t)lb * MD + m];
    Hsum[m] = s;
}

__global__ void transpose2_k(const float* __restrict__ H,
                             float* __restrict__ Ht, __bf16* __restrict__ Htb)
{
    __shared__ float tile[32][33];
    int mb = blockIdx.x * 32, lb = blockIdx.y * 32;
    int tx = threadIdx.x, ty = threadIdx.y;
    #pragma unroll
    for (int jj = 0; jj < 4; jj++)
        tile[ty + jj * 8][tx] = H[(size_t)(lb + ty + jj * 8) * MD + mb + tx];
    __syncthreads();
    #pragma unroll
    for (int jj = 0; jj < 4; jj++) {
        float v = tile[tx][ty + jj * 8];
        size_t idx = (size_t)(mb + ty + jj * 8) * LD + lb + tx;
        Ht[idx]  = v;
        Htb[idx] = (__bf16)v;
    }
}

__global__ void sumwa_k(const float* __restrict__ Wa, float* __restrict__ out)
{
    int tid = threadIdx.x;
    float v = Wa[tid] + Wa[tid + 256] + Wa[tid + 512] + Wa[tid + 768];
    #pragma unroll
    for (int off = 32; off >= 1; off >>= 1) v += __shfl_xor(v, off);
    __shared__ float r[4];
    if ((tid & 63) == 0) r[tid >> 6] = v;
    __syncthreads();
    if (tid == 0) out[0] = r[0] + r[1] + r[2] + r[3];
}

__global__ void final_copy_k(const float* __restrict__ Cmat, float* __restrict__ out)
{
    int m = blockIdx.x * 256 + threadIdx.x;
    out[m] = Cmat[m];              // C[0]
    out[1024 + m] = out[2048 + m]; // Hs[0]
}

// ---------------- dispatcher ----------------
static inline void mmx(const __bf16* Ab, const float* Af, int lda, int I,
                       const __bf16* Wb,
                       const float* bias, const float* X, int ldx, const float* add1,
                       float* C, float* C2, __bf16* C3, int ldc, int J, int K,
                       float scale, int epi, hipStream_t s)
{
    if (I <= 32) {
        gemv16<<<dim3(J / 4, (I + 15) / 16), 256, 0, s>>>(
            Af, lda, I, Wb, K, bias, X, ldx, add1, C, C2, C3, ldc, K, scale, epi);
    } else {
        int b128 = (J / 128) * ((I + 127) / 128);
        if (b128 >= 192)
            gemm_mfma<<<dim3(J / 128, (I + 127) / 128), 256, 0, s>>>(
                Ab, lda, Wb, bias, X, ldx, add1, C, C2, C3, ldc, I, K, scale, epi);
        else
            gemm64_mfma<<<dim3(J / 64, (I + 63) / 64), 256, 0, s>>>(
                Ab, lda, Wb, bias, X, ldx, add1, C, C2, C3, ldc, I, K, scale, epi);
    }
}

extern "C" void kernel_launch(void* const* d_in, const int* in_sizes, int n_in,
                              void* d_out, int out_size, void* d_ws, size_t ws_size,
                              hipStream_t stream)
{
    const float* inputs   = (const float*)d_in[0];
    const float* Hmat     = (const float*)d_in[1];
    const int*   children = (const int*)d_in[2];
    const float* ioux_w   = (const float*)d_in[3];
    const float* ioux_b   = (const float*)d_in[4];
    const float* iouh_w   = (const float*)d_in[5];
    const float* iouh_b   = (const float*)d_in[6];
    const float* fx_w     = (const float*)d_in[7];
    const float* fx_b     = (const float*)d_in[8];
    const float* fh_w     = (const float*)d_in[9];
    const float* fh_b     = (const float*)d_in[10];
    const float* Wa       = (const float*)d_in[11];
    const float* attnh_w  = (const float*)d_in[12];
    const float* attnh_b  = (const float*)d_in[13];

    float* out = (float*)d_out;
    float* Hs  = out + 2048;   // Hs (N*M) lives in d_out

    // ---- workspace layout ----
    float* p = (float*)d_ws;
    float* x_all   = p;  p += (size_t)ND * JZ;
    float* Zbuf    = p;  p += (size_t)ND * JZ;
    float* EHbuf   = p;  p += (size_t)LD * MD;
    float* Ht      = p;  p += (size_t)MD * LD;
    float* Cmat    = p;  p += (size_t)ND * MD;
    float* Hdelta  = p;  p += (size_t)ND * MD;
    float* hcell   = p;  p += (size_t)1024 * MD;
    float* Ehbuf   = p;  p += (size_t)1024 * MD;
    float* Sbuf    = p;  p += (size_t)1024 * LD;
    float* Hsum    = p;  p += MD;
    float* part16  = p;  p += 16 * MD;
    float* S_wa    = p;  p += 8;
    float* HsumWz  = p;  p += JZ;
    float* bx      = p;  p += JZ;
    __bf16* q = (__bf16*)p;
    __bf16* WzB    = q; q += (size_t)JZ * MD;
    __bf16* WxB    = q; q += (size_t)JZ * MD;
    __bf16* W1H    = q; q += (size_t)MD * MD;
    __bf16* W2H    = q; q += (size_t)MD * MD;
    __bf16* HtH    = q; q += (size_t)MD * LD;
    __bf16* inpB   = q; q += (size_t)ND * MD;
    __bf16* HmatB  = q; q += (size_t)LD * MD;
    __bf16* SbB    = q; q += (size_t)1024 * LD;
    __bf16* HdB    = q; q += (size_t)ND * MD;
    __bf16* hcellB = q; q += (size_t)1024 * MD;

    // ---- one-time conversions & precomputes ----
    cvt_all_k<<<2048, 256, 0, stream>>>(iouh_w, fh_w, ioux_w, fx_w, attnh_w, inputs, Hmat,
                                        WzB, WxB, W1H, W2H, inpB, HmatB);
    concat_bias_k<<<JZ / 256, 256, 0, stream>>>(ioux_b, fx_b, bx);
    transpose2_k<<<dim3(32, 32), dim3(32, 8), 0, stream>>>(Hmat, Ht, HtH);
    sumwa_k<<<1, 256, 0, stream>>>(Wa, S_wa);
    colsum_part_k<<<dim3(4, 16), 256, 0, stream>>>(Hmat, part16);
    colsum_reduce_k<<<4, 256, 0, stream>>>(part16, Hsum);
    gemvHsum<<<(3 * MD) / 4, 256, 0, stream>>>(Hsum, iouh_w, MD, HsumWz, MD);
    gemvHsum<<<MD / 4, 256, 0, stream>>>(Hsum, fh_w, MD, HsumWz + 3 * MD, MD);

    // x_all = inputs @ [ioux_w; fx_w]^T + [ioux_b; fx_b]
    mmx(inpB, inputs, MD, ND, WxB, bx, nullptr, 0, nullptr,
        x_all, nullptr, nullptr, JZ, JZ, MD, 1.0f, 0, stream);
    // EH = exp(2*(H@W2^T + attnh_b))
    mmx(HmatB, Hmat, MD, LD, W2H, attnh_b, nullptr, 0, nullptr,
        EHbuf, nullptr, nullptr, MD, MD, MD, 2.0f, 1, stream);

    static const int lv_t0[12] = {2047, 1023, 511, 255, 127, 63, 31, 15, 7, 3, 1, 0};
    static const int lv_B [12] = {1, 1024, 512, 256, 128, 64, 32, 16, 8, 4, 2, 1};

    // ---- level-parallel tree scan (deepest first), uniform 6-kernel pipeline ----
    for (int li = 0; li < 12; li++) {
        int t0 = lv_t0[li], B = lv_B[li];
        cell_finish_k<<<dim3(4, B), 256, 0, stream>>>(children, t0, Zbuf, HsumWz,
                                                      iouh_b, fh_b, x_all, Cmat, hcell, hcellB);
        // Eh = exp(2*hcell@W1^T)
        mmx(hcellB, hcell, MD, B, W1H, nullptr, nullptr, 0, nullptr,
            Ehbuf, nullptr, nullptr, MD, MD, MD, 2.0f, 1, stream);
        if (B >= 128)
            attn_s<64><<<dim3(LD / 64, B / 8), 512, 0, stream>>>(B, Ehbuf, EHbuf, S_wa, Wa, Sbuf);
        else if (B >= 16)
            attn_s<16><<<dim3(LD / 16, (B + 7) / 8), 512, 0, stream>>>(B, Ehbuf, EHbuf, S_wa, Wa, Sbuf);
        else
            attn_s<8><<<dim3(LD / 8, 1), 512, 0, stream>>>(B, Ehbuf, EHbuf, S_wa, Wa, Sbuf);
        softmax_rows<<<B, 256, 0, stream>>>(Sbuf, SbB);
        // FIN: Hs = Hsum - p@H + hcell ; Hdelta/HdB = hcell - p@H
        mmx(SbB, Sbuf, LD, B, HtH, nullptr, hcell, MD, Hsum,
            Hs + (size_t)t0 * MD, Hdelta + (size_t)t0 * MD, HdB + (size_t)t0 * MD,
            MD, MD, LD, 1.0f, 2, stream);
        // Z[t] = Hdelta[t] @ [iouh_w; fh_w]^T  (not needed for root)
        if (li < 11)
            mmx(HdB + (size_t)t0 * MD, Hdelta + (size_t)t0 * MD, MD, B, WzB,
                nullptr, nullptr, 0, nullptr,
                Zbuf + (size_t)t0 * JZ, nullptr, nullptr, JZ, JZ, MD, 1.0f, 0, stream);
    }
    final_copy_k<<<4, 256, 0, stream>>>(Cmat, out);
}

// Round 15
// 1146.986 us; speedup vs baseline: 1.7774x; 1.7774x over previous
//
#include <hip/hip_runtime.h>
#include <hip/hip_bf16.h>

#define MD 1024   // M
#define LD 1024   // L
#define ND 2048   // N
#define JZ 4096   // combined [iou|f] width

typedef __bf16 bf16x8 __attribute__((ext_vector_type(8)));
typedef __bf16 bf16x4 __attribute__((ext_vector_type(4)));
typedef float  f32x4  __attribute__((ext_vector_type(4)));

__device__ __forceinline__ float fsig(float x)  { return 1.0f / (1.0f + __expf(-x)); }
__device__ __forceinline__ float ftanh_(float x){ float e = __expf(2.0f * x); return 1.0f - 2.0f / (e + 1.0f); }

__device__ __forceinline__ bf16x8 bzero8() {
    bf16x8 z;
    #pragma unroll
    for (int q = 0; q < 8; q++) z[q] = (__bf16)0.f;
    return z;
}

// async 16B global -> LDS (dest = wave-uniform base + lane*16)
__device__ __forceinline__ void gload16(const __bf16* g, __bf16* l)
{
    __builtin_amdgcn_global_load_lds(
        (const __attribute__((address_space(1))) void*)g,
        (__attribute__((address_space(3))) void*)l, 16, 0, 0);
}

// ---------------- merged f32 -> bf16 conversions (one launch) ----------------
__global__ void cvt_all_k(const float* __restrict__ iouh_w, const float* __restrict__ fh_w,
                          const float* __restrict__ ioux_w, const float* __restrict__ fx_w,
                          const float* __restrict__ attnh_w, const float* __restrict__ inputs,
                          const float* __restrict__ Hmat,
                          __bf16* __restrict__ WzB, __bf16* __restrict__ WxB,
                          __bf16* __restrict__ W1H, __bf16* __restrict__ W2H,
                          __bf16* __restrict__ inpB, __bf16* __restrict__ HmatB)
{
    const size_t MM = (size_t)MD * MD;
    const size_t b0 = 3 * MM, b1 = 4 * MM, b2 = 7 * MM, b3 = 8 * MM;
    const size_t b4 = 9 * MM, b5 = 10 * MM, b6 = 12 * MM, b7 = 13 * MM;
    for (size_t idx = (size_t)blockIdx.x * 256 + threadIdx.x; idx < b7;
         idx += (size_t)gridDim.x * 256) {
        if (idx < b1) {
            WzB[idx] = (__bf16)((idx < b0) ? iouh_w[idx] : fh_w[idx - b0]);
        } else if (idx < b3) {
            size_t r = idx - b1;
            WxB[r] = (__bf16)((idx < b2) ? ioux_w[r] : fx_w[idx - b2]);
        } else if (idx < b4) {
            size_t r = idx - b3; size_t j = r >> 10, k = r & (MD - 1);
            W1H[r] = (__bf16)attnh_w[j * 2 * MD + k];
        } else if (idx < b5) {
            size_t r = idx - b4; size_t j = r >> 10, k = r & (MD - 1);
            W2H[r] = (__bf16)attnh_w[j * 2 * MD + MD + k];
        } else if (idx < b6) {
            size_t r = idx - b5;
            inpB[r] = (__bf16)inputs[r];
        } else {
            size_t r = idx - b6;
            HmatB[r] = (__bf16)Hmat[r];
        }
    }
}

__global__ void concat_bias_k(const float* __restrict__ a, const float* __restrict__ b,
                              float* __restrict__ dst)
{
    int i = blockIdx.x * 256 + threadIdx.x;
    dst[i] = (i < 3 * MD) ? a[i] : b[i - 3 * MD];
}

// epilogue modes:
//  0: (acc+bias)*scale (+X)
//  1: exp(clamp((acc+bias)*scale (+X), +-80))
//  2: FIN: C = add1[col] - acc + X ; C2 = X - acc ; C3 = bf16(X - acc)
// ---------------- bf16 MFMA NT GEMM, 128x128 tile ----------------
__global__ __launch_bounds__(256) void gemm_mfma(
    const __bf16* __restrict__ Ab, int lda,
    const __bf16* __restrict__ Wh,
    const float* __restrict__ bias,
    const float* __restrict__ X, int ldx, const float* __restrict__ add1,
    float* __restrict__ C, float* __restrict__ C2, __bf16* __restrict__ C3, int ldc,
    int I, int K, float scale, int epi)
{
    __shared__ __align__(16) __bf16 Ash[128][4][8];
    __shared__ __align__(16) __bf16 Bsh[128][4][8];
    const int tid = threadIdx.x;
    const int j0 = blockIdx.x * 128, i0 = blockIdx.y * 128;
    const int lane = tid & 63, wv = tid >> 6;
    const int wm = wv >> 1, wn = wv & 1;
    const int g = lane >> 4, fr = lane & 15;

    f32x4 acc[4][4];
    #pragma unroll
    for (int m = 0; m < 4; m++)
        #pragma unroll
        for (int n = 0; n < 4; n++)
            acc[m][n] = (f32x4){0.f, 0.f, 0.f, 0.f};

    const int srow = tid >> 2;
    const int sg   = tid & 3;
    int ar0 = i0 + srow;       if (ar0 >= I) ar0 = I - 1;
    int ar1 = i0 + srow + 64;  if (ar1 >= I) ar1 = I - 1;
    const __bf16* agp0 = Ab + (size_t)ar0 * lda + sg * 8;
    const __bf16* agp1 = Ab + (size_t)ar1 * lda + sg * 8;
    const __bf16* wgp0 = Wh + (size_t)(j0 + srow) * K + sg * 8;
    const __bf16* wgp1 = Wh + (size_t)(j0 + srow + 64) * K + sg * 8;
    __bf16* aD0 = &Ash[wv * 16][0][0];
    __bf16* aD1 = &Ash[64 + wv * 16][0][0];
    __bf16* bD0 = &Bsh[wv * 16][0][0];
    __bf16* bD1 = &Bsh[64 + wv * 16][0][0];

    for (int kt = 0; kt < K; kt += 32) {
        __syncthreads();
        gload16(agp0 + kt, aD0);
        gload16(agp1 + kt, aD1);
        gload16(wgp0 + kt, bD0);
        gload16(wgp1 + kt, bD1);
        __syncthreads();

        bf16x8 ah[4], bh[4];
        #pragma unroll
        for (int m = 0; m < 4; m++) ah[m] = *(bf16x8*)&Ash[wm * 64 + m * 16 + fr][g][0];
        #pragma unroll
        for (int n = 0; n < 4; n++) bh[n] = *(bf16x8*)&Bsh[wn * 64 + n * 16 + fr][g][0];
        #pragma unroll
        for (int m = 0; m < 4; m++)
            #pragma unroll
            for (int n = 0; n < 4; n++)
                acc[m][n] = __builtin_amdgcn_mfma_f32_16x16x32_bf16(ah[m], bh[n], acc[m][n], 0, 0, 0);
    }

    #pragma unroll
    for (int m = 0; m < 4; m++) {
        int rbase = i0 + wm * 64 + m * 16 + g * 4;
        #pragma unroll
        for (int nn = 0; nn < 4; nn++) {
            int col = j0 + wn * 64 + nn * 16 + fr;
            float b = bias ? bias[col] : 0.f;
            #pragma unroll
            for (int j = 0; j < 4; j++) {
                int r = rbase + j;
                if (r >= I) continue;
                float a = acc[m][nn][j];
                if (epi == 2) {
                    float hc = X[(size_t)r * ldx + col];
                    C[(size_t)r * ldc + col]  = add1[col] - a + hc;
                    float d = hc - a;
                    C2[(size_t)r * ldc + col] = d;
                    C3[(size_t)r * ldc + col] = (__bf16)d;
                } else {
                    float v = (a + b) * scale;
                    if (X) v += X[(size_t)r * ldx + col];
                    if (epi == 1) v = __expf(fminf(fmaxf(v, -80.f), 80.f));
                    C[(size_t)r * ldc + col] = v;
                }
            }
        }
    }
}

// ---------------- bf16 MFMA NT GEMM, 64x64 tile ----------------
__global__ __launch_bounds__(256) void gemm64_mfma(
    const __bf16* __restrict__ Ab, int lda,
    const __bf16* __restrict__ Wh,
    const float* __restrict__ bias,
    const float* __restrict__ X, int ldx, const float* __restrict__ add1,
    float* __restrict__ C, float* __restrict__ C2, __bf16* __restrict__ C3, int ldc,
    int I, int K, float scale, int epi)
{
    __shared__ __align__(16) __bf16 Ash[64][4][8];
    __shared__ __align__(16) __bf16 Bsh[64][4][8];
    const int tid = threadIdx.x;
    const int j0 = blockIdx.x * 64, i0 = blockIdx.y * 64;
    const int lane = tid & 63, wv = tid >> 6;
    const int wm = wv >> 1, wn = wv & 1;
    const int g = lane >> 4, fr = lane & 15;

    f32x4 acc[2][2];
    #pragma unroll
    for (int m = 0; m < 2; m++)
        #pragma unroll
        for (int n = 0; n < 2; n++)
            acc[m][n] = (f32x4){0.f, 0.f, 0.f, 0.f};

    const int srow = tid >> 2;
    const int sg   = tid & 3;
    int ar = i0 + srow;  if (ar >= I) ar = I - 1;
    const __bf16* agp = Ab + (size_t)ar * lda + sg * 8;
    const __bf16* wgp = Wh + (size_t)(j0 + srow) * K + sg * 8;
    __bf16* aD = &Ash[wv * 16][0][0];
    __bf16* bD = &Bsh[wv * 16][0][0];

    for (int kt = 0; kt < K; kt += 32) {
        __syncthreads();
        gload16(agp + kt, aD);
        gload16(wgp + kt, bD);
        __syncthreads();

        bf16x8 ah[2], bh[2];
        #pragma unroll
        for (int m = 0; m < 2; m++) ah[m] = *(bf16x8*)&Ash[wm * 32 + m * 16 + fr][g][0];
        #pragma unroll
        for (int n = 0; n < 2; n++) bh[n] = *(bf16x8*)&Bsh[wn * 32 + n * 16 + fr][g][0];
        #pragma unroll
        for (int m = 0; m < 2; m++)
            #pragma unroll
            for (int n = 0; n < 2; n++)
                acc[m][n] = __builtin_amdgcn_mfma_f32_16x16x32_bf16(ah[m], bh[n], acc[m][n], 0, 0, 0);
    }

    #pragma unroll
    for (int m = 0; m < 2; m++) {
        int rbase = i0 + wm * 32 + m * 16 + g * 4;
        #pragma unroll
        for (int nn = 0; nn < 2; nn++) {
            int col = j0 + wn * 32 + nn * 16 + fr;
            float b = bias ? bias[col] : 0.f;
            #pragma unroll
            for (int j = 0; j < 4; j++) {
                int r = rbase + j;
                if (r >= I) continue;
                float a = acc[m][nn][j];
                if (epi == 2) {
                    float hc = X[(size_t)r * ldx + col];
                    C[(size_t)r * ldc + col]  = add1[col] - a + hc;
                    float d = hc - a;
                    C2[(size_t)r * ldc + col] = d;
                    C3[(size_t)r * ldc + col] = (__bf16)d;
                } else {
                    float v = (a + b) * scale;
                    if (X) v += X[(size_t)r * ldx + col];
                    if (epi == 1) v = __expf(fminf(fmaxf(v, -80.f), 80.f));
                    C[(size_t)r * ldc + col] = v;
                }
            }
        }
    }
}

// ---------------- i-tiled batched GEMV (f32 A x bf16 W), tail I<=32 ----------------
__global__ __launch_bounds__(256) void gemv16(
    const float* __restrict__ Af, int lda, int I,
    const __bf16* __restrict__ Wb, int ldw,
    const float* __restrict__ bias,
    const float* __restrict__ X, int ldx, const float* __restrict__ add1,
    float* __restrict__ C, float* __restrict__ C2, __bf16* __restrict__ C3, int ldc,
    int K, float scale, int epi)
{
    const int wv = threadIdx.x >> 6, lane = threadIdx.x & 63;
    const int j = blockIdx.x * 4 + wv;
    const int i0 = blockIdx.y * 16;
    const int nI = (I - i0 < 16) ? (I - i0) : 16;
    float acc[16];
    #pragma unroll
    for (int i = 0; i < 16; i++) acc[i] = 0.0f;
    const __bf16* wp = Wb + (size_t)j * ldw + lane * 4;
    const float*  ap = Af + (size_t)i0 * lda + lane * 4;
    for (int k = lane * 4; k < K; k += 256, wp += 256, ap += 256) {
        bf16x4 w4 = *(const bf16x4*)wp;
        float w0 = (float)w4[0], w1 = (float)w4[1], w2 = (float)w4[2], w3 = (float)w4[3];
        const float* a = ap;
        #pragma unroll
        for (int i = 0; i < 16; i++, a += lda) {
            if (i < nI) {
                float4 a4 = *(const float4*)a;
                acc[i] += a4.x * w0 + a4.y * w1 + a4.z * w2 + a4.w * w3;
            }
        }
    }
    #pragma unroll
    for (int i = 0; i < 16; i++) {
        if (i < nI) {
            float s = acc[i];
            #pragma unroll
            for (int off = 32; off >= 1; off >>= 1) s += __shfl_xor(s, off);
            if (lane == 0) {
                int r = i0 + i;
                if (epi == 2) {
                    float hc = X[(size_t)r * ldx + j];
                    C[(size_t)r * ldc + j]  = add1[j] - s + hc;
                    float d = hc - s;
                    C2[(size_t)r * ldc + j] = d;
                    C3[(size_t)r * ldc + j] = (__bf16)d;
                } else {
                    float v = (s + (bias ? bias[j] : 0.f)) * scale;
                    if (X) v += X[(size_t)r * ldx + j];
                    if (epi == 1) v = __expf(fminf(fmaxf(v, -80.f), 80.f));
                    C[(size_t)r * ldc + j] = v;
                }
            }
        }
    }
}

// ---------------- exact f32 GEMV (HsumWz precompute only, I=1) ----------------
__global__ __launch_bounds__(256) void gemvHsum(
    const float* __restrict__ Af,
    const float* __restrict__ Wf, int ldw,
    float* __restrict__ C, int K)
{
    const int wv = threadIdx.x >> 6, lane = threadIdx.x & 63;
    const int j = blockIdx.x * 4 + wv;
    float a = 0.f;
    for (int k = lane * 4; k < K; k += 256) {
        float4 w4 = *(const float4*)(Wf + (size_t)j * ldw + k);
        float4 a4 = *(const float4*)(Af + k);
        a += a4.x * w4.x + a4.y * w4.y + a4.z * w4.z + a4.w * w4.w;
    }
    #pragma unroll
    for (int off = 32; off >= 1; off >>= 1) a += __shfl_xor(a, off);
    if (lane == 0) C[j] = a;
}

// ---------------- attention scores via exp tables (R12 proven form) ----------------
template<int LTILE>
__global__ __launch_bounds__(512) void attn_s(
    int B, const float* __restrict__ Eh,
    const float* __restrict__ EH,
    const float* __restrict__ s_wa_sum,
    const float* __restrict__ Wa,
    float* __restrict__ S)
{
    __shared__ float s_e[8][MD];
    __shared__ float s_wa[MD];
    const int lt = blockIdx.x * LTILE;
    const int b0 = blockIdx.y * 8;
    const int nt = (B - b0 < 8) ? (B - b0) : 8;
    for (int idx = threadIdx.x; idx < MD; idx += 512) s_wa[idx] = Wa[idx];
    for (int i = 0; i < nt; i++)
        for (int idx = threadIdx.x; idx < MD; idx += 512)
            s_e[i][idx] = Eh[(size_t)(b0 + i) * MD + idx];
    __syncthreads();
    const int wv = threadIdx.x >> 6, lane = threadIdx.x & 63;
    const float swa = s_wa_sum[0];
    if (LTILE >= 16) {
        for (int l = lt + wv; l < lt + LTILE; l += 16) {
            float accA[8] = {}, accB[8] = {};
            const float* erA = EH + (size_t)l * MD;
            const float* erB = EH + (size_t)(l + 8) * MD;
            for (int mc = 0; mc < MD; mc += 256) {
                const int m = mc + lane * 4;
                float4 evA = *(const float4*)(erA + m);
                float4 evB = *(const float4*)(erB + m);
                float4 wa4 = *(const float4*)&s_wa[m];
                #pragma unroll
                for (int i = 0; i < 8; i++) {
                    if (i < nt) {
                        float4 se = *(const float4*)&s_e[i][m];
                        accA[i] = fmaf(wa4.x, __builtin_amdgcn_rcpf(fmaf(se.x, evA.x, 1.0f)), accA[i]);
                        accA[i] = fmaf(wa4.y, __builtin_amdgcn_rcpf(fmaf(se.y, evA.y, 1.0f)), accA[i]);
                        accA[i] = fmaf(wa4.z, __builtin_amdgcn_rcpf(fmaf(se.z, evA.z, 1.0f)), accA[i]);
                        accA[i] = fmaf(wa4.w, __builtin_amdgcn_rcpf(fmaf(se.w, evA.w, 1.0f)), accA[i]);
                        accB[i] = fmaf(wa4.x, __builtin_amdgcn_rcpf(fmaf(se.x, evB.x, 1.0f)), accB[i]);
                        accB[i] = fmaf(wa4.y, __builtin_amdgcn_rcpf(fmaf(se.y, evB.y, 1.0f)), accB[i]);
                        accB[i] = fmaf(wa4.z, __builtin_amdgcn_rcpf(fmaf(se.z, evB.z, 1.0f)), accB[i]);
                        accB[i] = fmaf(wa4.w, __builtin_amdgcn_rcpf(fmaf(se.w, evB.w, 1.0f)), accB[i]);
                    }
                }
            }
            #pragma unroll
            for (int i = 0; i < 8; i++) {
                if (i < nt) {
                    float vA = accA[i], vB = accB[i];
                    #pragma unroll
                    for (int off = 32; off >= 1; off >>= 1) {
                        vA += __shfl_xor(vA, off);
                        vB += __shfl_xor(vB, off);
                    }
                    if (lane == 0) {
                        S[(size_t)(b0 + i) * LD + l]     = swa - 2.0f * vA;
                        S[(size_t)(b0 + i) * LD + l + 8] = swa - 2.0f * vB;
                    }
                }
            }
        }
    } else {
        for (int l = lt + wv; l < lt + LTILE; l += 8) {
            float acc[8] = {};
            const float* er = EH + (size_t)l * MD;
            for (int mc = 0; mc < MD; mc += 256) {
                const int m = mc + lane * 4;
                float4 ev  = *(const float4*)(er + m);
                float4 wa4 = *(const float4*)&s_wa[m];
                #pragma unroll
                for (int i = 0; i < 8; i++) {
                    if (i < nt) {
                        float4 se = *(const float4*)&s_e[i][m];
                        acc[i] = fmaf(wa4.x, __builtin_amdgcn_rcpf(fmaf(se.x, ev.x, 1.0f)), acc[i]);
                        acc[i] = fmaf(wa4.y, __builtin_amdgcn_rcpf(fmaf(se.y, ev.y, 1.0f)), acc[i]);
                        acc[i] = fmaf(wa4.z, __builtin_amdgcn_rcpf(fmaf(se.z, ev.z, 1.0f)), acc[i]);
                        acc[i] = fmaf(wa4.w, __builtin_amdgcn_rcpf(fmaf(se.w, ev.w, 1.0f)), acc[i]);
                    }
                }
            }
            #pragma unroll
            for (int i = 0; i < 8; i++) {
                if (i < nt) {
                    float v = acc[i];
                    #pragma unroll
                    for (int off = 32; off >= 1; off >>= 1) v += __shfl_xor(v, off);
                    if (lane == 0) S[(size_t)(b0 + i) * LD + l] = swa - 2.0f * v;
                }
            }
        }
    }
}

// ---------------- softmax (f32 + bf16 copies of P) ----------------
__global__ __launch_bounds__(256) void softmax_rows(float* __restrict__ S, __bf16* __restrict__ Sb)
{
    float* row = S + (size_t)blockIdx.x * LD;
    __bf16* rb = Sb + (size_t)blockIdx.x * LD;
    const int tid = threadIdx.x;
    const int wv = tid >> 6, lane = tid & 63;
    float v0 = row[tid], v1 = row[tid + 256], v2 = row[tid + 512], v3 = row[tid + 768];
    float mx = fmaxf(fmaxf(v0, v1), fmaxf(v2, v3));
    #pragma unroll
    for (int off = 32; off >= 1; off >>= 1) mx = fmaxf(mx, __shfl_xor(mx, off));
    __shared__ float r1[4], r2[4];
    if (lane == 0) r1[wv] = mx;
    __syncthreads();
    mx = fmaxf(fmaxf(r1[0], r1[1]), fmaxf(r1[2], r1[3]));
    float e0 = __expf(v0 - mx), e1 = __expf(v1 - mx), e2 = __expf(v2 - mx), e3 = __expf(v3 - mx);
    float sm = e0 + e1 + e2 + e3;
    #pragma unroll
    for (int off = 32; off >= 1; off >>= 1) sm += __shfl_xor(sm, off);
    if (lane == 0) r2[wv] = sm;
    __syncthreads();
    sm = r2[0] + r2[1] + r2[2] + r2[3];
    float inv = 1.0f / sm;
    float p0 = e0 * inv, p1 = e1 * inv, p2 = e2 * inv, p3 = e3 * inv;
    row[tid] = p0; row[tid + 256] = p1; row[tid + 512] = p2; row[tid + 768] = p3;
    rb[tid] = (__bf16)p0; rb[tid + 256] = (__bf16)p1;
    rb[tid + 512] = (__bf16)p2; rb[tid + 768] = (__bf16)p3;
}

// ---------------- cell finish ----------------
__global__ void cell_finish_k(const int* __restrict__ children, int t0,
    const float* __restrict__ Z, const float* __restrict__ HsumWz,
    const float* __restrict__ iouh_b, const float* __restrict__ fh_b,
    const float* __restrict__ x_all,
    float* __restrict__ Cmat, float* __restrict__ hcell, __bf16* __restrict__ hcellB)
{
    int b = blockIdx.y;
    int m = blockIdx.x * 256 + threadIdx.x;
    int t = t0 + b;
    int c0 = children[2 * t], c1 = children[2 * t + 1];
    float cnt = (float)((c0 >= 0) + (c1 >= 0));
    const float* z0 = (c0 >= 0) ? Z + (size_t)c0 * JZ : nullptr;
    const float* z1 = (c1 >= 0) ? Z + (size_t)c1 * JZ : nullptr;
    const float* xr = x_all + (size_t)t * JZ;

    float zi = 0.f, zo = 0.f, zu = 0.f;
    if (z0) { zi += z0[m]; zo += z0[MD + m]; zu += z0[2 * MD + m]; }
    if (z1) { zi += z1[m]; zo += z1[MD + m]; zu += z1[2 * MD + m]; }
    float iv = fsig (zi + cnt * HsumWz[m]           + iouh_b[m]           + xr[m]);
    float ov = fsig (zo + cnt * HsumWz[MD + m]      + iouh_b[MD + m]      + xr[MD + m]);
    float uv = ftanh_(zu + cnt * HsumWz[2 * MD + m] + iouh_b[2 * MD + m]  + xr[2 * MD + m]);

    float hwf = HsumWz[3 * MD + m] + fh_b[m] + xr[3 * MD + m];
    float c = iv * uv;
    if (c0 >= 0) c += fsig(z0[3 * MD + m] + hwf) * Cmat[(size_t)c0 * MD + m];
    if (c1 >= 0) c += fsig(z1[3 * MD + m] + hwf) * Cmat[(size_t)c1 * MD + m];
    Cmat[(size_t)t * MD + m] = c;
    float h = ov * ftanh_(c);
    hcell[(size_t)b * MD + m] = h;
    hcellB[(size_t)b * MD + m] = (__bf16)h;
}

// ---------------- misc precompute ----------------
__global__ void colsum_part_k(const float* __restrict__ H, float* __restrict__ part)
{
    int m = blockIdx.x * 256 + threadIdx.x;
    int lb = blockIdx.y;
    float s = 0.f;
    for (int l = lb * 64; l < lb * 64 + 64; l++) s += H[(size_t)l * MD + m];
    part[(size_t)lb * MD + m] = s;
}

__global__ void colsum_reduce_k(const float* __restrict__ part, float* __restrict__ Hsum)
{
    int m = blockIdx.x * 256 + threadIdx.x;
    float s = 0.f;
    for (int lb = 0; lb < 16; lb++) s += part[(size_t)lb * MD + m];
    Hsum[m] = s;
}

__global__ void transpose2_k(const float* __restrict__ H,
                             float* __restrict__ Ht, __bf16* __restrict__ Htb)
{
    __shared__ float tile[32][33];
    int mb = blockIdx.x * 32, lb = blockIdx.y * 32;
    int tx = threadIdx.x, ty = threadIdx.y;
    #pragma unroll
    for (int jj = 0; jj < 4; jj++)
        tile[ty + jj * 8][tx] = H[(size_t)(lb + ty + jj * 8) * MD + mb + tx];
    __syncthreads();
    #pragma unroll
    for (int jj = 0; jj < 4; jj++) {
        float v = tile[tx][ty + jj * 8];
        size_t idx = (size_t)(mb + ty + jj * 8) * LD + lb + tx;
        Ht[idx]  = v;
        Htb[idx] = (__bf16)v;
    }
}

__global__ void sumwa_k(const float* __restrict__ Wa, float* __restrict__ out)
{
    int tid = threadIdx.x;
    float v = Wa[tid] + Wa[tid + 256] + Wa[tid + 512] + Wa[tid + 768];
    #pragma unroll
    for (int off = 32; off >= 1; off >>= 1) v += __shfl_xor(v, off);
    __shared__ float r[4];
    if ((tid & 63) == 0) r[tid >> 6] = v;
    __syncthreads();
    if (tid == 0) out[0] = r[0] + r[1] + r[2] + r[3];
}

__global__ void final_copy_k(const float* __restrict__ Cmat, float* __restrict__ out)
{
    int m = blockIdx.x * 256 + threadIdx.x;
    out[m] = Cmat[m];              // C[0]
    out[1024 + m] = out[2048 + m]; // Hs[0]
}

// ---------------- dispatcher ----------------
static inline void mmx(const __bf16* Ab, const float* Af, int lda, int I,
                       const __bf16* Wb,
                       const float* bias, const float* X, int ldx, const float* add1,
                       float* C, float* C2, __bf16* C3, int ldc, int J, int K,
                       float scale, int epi, hipStream_t s)
{
    if (I <= 32) {
        gemv16<<<dim3(J / 4, (I + 15) / 16), 256, 0, s>>>(
            Af, lda, I, Wb, K, bias, X, ldx, add1, C, C2, C3, ldc, K, scale, epi);
    } else {
        int b128 = (J / 128) * ((I + 127) / 128);
        if (b128 >= 192)
            gemm_mfma<<<dim3(J / 128, (I + 127) / 128), 256, 0, s>>>(
                Ab, lda, Wb, bias, X, ldx, add1, C, C2, C3, ldc, I, K, scale, epi);
        else
            gemm64_mfma<<<dim3(J / 64, (I + 63) / 64), 256, 0, s>>>(
                Ab, lda, Wb, bias, X, ldx, add1, C, C2, C3, ldc, I, K, scale, epi);
    }
}

extern "C" void kernel_launch(void* const* d_in, const int* in_sizes, int n_in,
                              void* d_out, int out_size, void* d_ws, size_t ws_size,
                              hipStream_t stream)
{
    const float* inputs   = (const float*)d_in[0];
    const float* Hmat     = (const float*)d_in[1];
    const int*   children = (const int*)d_in[2];
    const float* ioux_w   = (const float*)d_in[3];
    const float* ioux_b   = (const float*)d_in[4];
    const float* iouh_w   = (const float*)d_in[5];
    const float* iouh_b   = (const float*)d_in[6];
    const float* fx_w     = (const float*)d_in[7];
    const float* fx_b     = (const float*)d_in[8];
    const float* fh_w     = (const float*)d_in[9];
    const float* fh_b     = (const float*)d_in[10];
    const float* Wa       = (const float*)d_in[11];
    const float* attnh_w  = (const float*)d_in[12];
    const float* attnh_b  = (const float*)d_in[13];

    float* out = (float*)d_out;
    float* Hs  = out + 2048;   // Hs (N*M) lives in d_out

    // ---- workspace layout ----
    float* p = (float*)d_ws;
    float* x_all   = p;  p += (size_t)ND * JZ;
    float* Zbuf    = p;  p += (size_t)ND * JZ;
    float* EHbuf   = p;  p += (size_t)LD * MD;
    float* Ht      = p;  p += (size_t)MD * LD;
    float* Cmat    = p;  p += (size_t)ND * MD;
    float* Hdelta  = p;  p += (size_t)ND * MD;
    float* hcell   = p;  p += (size_t)1024 * MD;
    float* Ehbuf   = p;  p += (size_t)1024 * MD;
    float* Sbuf    = p;  p += (size_t)1024 * LD;
    float* Hsum    = p;  p += MD;
    float* part16  = p;  p += 16 * MD;
    float* S_wa    = p;  p += 8;
    float* HsumWz  = p;  p += JZ;
    float* bx      = p;  p += JZ;
    __bf16* q = (__bf16*)p;
    __bf16* WzB    = q; q += (size_t)JZ * MD;
    __bf16* WxB    = q; q += (size_t)JZ * MD;
    __bf16* W1H    = q; q += (size_t)MD * MD;
    __bf16* W2H    = q; q += (size_t)MD * MD;
    __bf16* HtH    = q; q += (size_t)MD * LD;
    __bf16* inpB   = q; q += (size_t)ND * MD;
    __bf16* HmatB  = q; q += (size_t)LD * MD;
    __bf16* SbB    = q; q += (size_t)1024 * LD;
    __bf16* HdB    = q; q += (size_t)ND * MD;
    __bf16* hcellB = q; q += (size_t)1024 * MD;

    // ---- one-time conversions & precomputes ----
    cvt_all_k<<<2048, 256, 0, stream>>>(iouh_w, fh_w, ioux_w, fx_w, attnh_w, inputs, Hmat,
                                        WzB, WxB, W1H, W2H, inpB, HmatB);
    concat_bias_k<<<JZ / 256, 256, 0, stream>>>(ioux_b, fx_b, bx);
    transpose2_k<<<dim3(32, 32), dim3(32, 8), 0, stream>>>(Hmat, Ht, HtH);
    sumwa_k<<<1, 256, 0, stream>>>(Wa, S_wa);
    colsum_part_k<<<dim3(4, 16), 256, 0, stream>>>(Hmat, part16);
    colsum_reduce_k<<<4, 256, 0, stream>>>(part16, Hsum);
    gemvHsum<<<(3 * MD) / 4, 256, 0, stream>>>(Hsum, iouh_w, MD, HsumWz, MD);
    gemvHsum<<<MD / 4, 256, 0, stream>>>(Hsum, fh_w, MD, HsumWz + 3 * MD, MD);

    // x_all = inputs @ [ioux_w; fx_w]^T + [ioux_b; fx_b]
    mmx(inpB, inputs, MD, ND, WxB, bx, nullptr, 0, nullptr,
        x_all, nullptr, nullptr, JZ, JZ, MD, 1.0f, 0, stream);
    // EH = exp(2*(H@W2^T + attnh_b))
    mmx(HmatB, Hmat, MD, LD, W2H, attnh_b, nullptr, 0, nullptr,
        EHbuf, nullptr, nullptr, MD, MD, MD, 2.0f, 1, stream);

    static const int lv_t0[12] = {2047, 1023, 511, 255, 127, 63, 31, 15, 7, 3, 1, 0};
    static const int lv_B [12] = {1, 1024, 512, 256, 128, 64, 32, 16, 8, 4, 2, 1};

    // ---- level-parallel tree scan (deepest first), uniform 6-kernel pipeline ----
    for (int li = 0; li < 12; li++) {
        int t0 = lv_t0[li], B = lv_B[li];
        cell_finish_k<<<dim3(4, B), 256, 0, stream>>>(children, t0, Zbuf, HsumWz,
                                                      iouh_b, fh_b, x_all, Cmat, hcell, hcellB);
        // Eh = exp(2*hcell@W1^T)
        mmx(hcellB, hcell, MD, B, W1H, nullptr, nullptr, 0, nullptr,
            Ehbuf, nullptr, nullptr, MD, MD, MD, 2.0f, 1, stream);
        if (B >= 128)
            attn_s<64><<<dim3(LD / 64, B / 8), 512, 0, stream>>>(B, Ehbuf, EHbuf, S_wa, Wa, Sbuf);
        else if (B >= 16)
            attn_s<16><<<dim3(LD / 16, (B + 7) / 8), 512, 0, stream>>>(B, Ehbuf, EHbuf, S_wa, Wa, Sbuf);
        else
            attn_s<8><<<dim3(LD / 8, 1), 512, 0, stream>>>(B, Ehbuf, EHbuf, S_wa, Wa, Sbuf);
        softmax_rows<<<B, 256, 0, stream>>>(Sbuf, SbB);
        // FIN: Hs = Hsum - p@H + hcell ; Hdelta/HdB = hcell - p@H
        mmx(SbB, Sbuf, LD, B, HtH, nullptr, hcell, MD, Hsum,
            Hs + (size_t)t0 * MD, Hdelta + (size_t)t0 * MD, HdB + (size_t)t0 * MD,
            MD, MD, LD, 1.0f, 2, stream);
        // Z[t] = Hdelta[t] @ [iouh_w; fh_w]^T  (not needed for root)
        if (li < 11)
            mmx(HdB + (size_t)t0 * MD, Hdelta + (size_t)t0 * MD, MD, B, WzB,
                nullptr, nullptr, 0, nullptr,
                Zbuf + (size_t)t0 * JZ, nullptr, nullptr, JZ, JZ, MD, 1.0f, 0, stream);
    }
    final_copy_k<<<4, 256, 0, stream>>>(Cmat, out);
}